// Round 16
// baseline (187.312 us; speedup 1.0000x reference)
//
#include <hip/hip_runtime.h>
#include <hip/hip_bf16.h>

typedef __attribute__((ext_vector_type(8))) short bf16x8;
typedef __attribute__((ext_vector_type(4))) float f32x4;

static __device__ __forceinline__ unsigned short f2bf(float f) {
    unsigned u = __builtin_bit_cast(unsigned, f);
    unsigned rounding = 0x7fffu + ((u >> 16) & 1u);
    u += rounding;
    return (unsigned short)(u >> 16);
}

static __device__ __forceinline__ void async_copy16(const void* g, void* l) {
    __builtin_amdgcn_global_load_lds(
        (const __attribute__((address_space(1))) unsigned int*)g,
        (__attribute__((address_space(3))) unsigned int*)l,
        16, 0, 0);
}

#define BARRIER() __builtin_amdgcn_s_barrier()
#define VMCNT(N) do { asm volatile("s_waitcnt vmcnt(" #N ")" ::: "memory"); \
                      __builtin_amdgcn_sched_barrier(0); } while (0)
#define VM0() VMCNT(0)

// fast erf-gelu via tanh approximation (|err| <= ~3e-3, threshold margin 0.07+)
static __device__ __forceinline__ float fast_gelu(float y) {
    float u = 0.7978845608028654f * y * (1.0f + 0.044715f * y * y);
    float au = fminf(fabsf(u), 9.0f);
    float e = __expf(-2.0f * au);
    float th = (1.0f - e) * __builtin_amdgcn_rcpf(1.0f + e);
    th = (u < 0.0f) ? -th : th;
    return 0.5f * y * (1.0f + th);
}

// ---------------- merged prep: LN(+bf16 cast) and W->Wt transpose-cast --------
__global__ __launch_bounds__(256) void prep_kernel(
    const float* __restrict__ x, const float* __restrict__ gamma,
    const float* __restrict__ beta, unsigned short* __restrict__ Aout,
    const float* __restrict__ W, unsigned short* __restrict__ Wt) {
    __shared__ float smem[33 * 32];
    const int b = blockIdx.x;
    const int t = threadIdx.x;

    if (b < 16384) {
        const int row = b;
        const float4 v = ((const float4*)(x + (size_t)row * 1024))[t];
        float s  = v.x + v.y + v.z + v.w;
        float ss = v.x * v.x + v.y * v.y + v.z * v.z + v.w * v.w;
        #pragma unroll
        for (int off = 32; off; off >>= 1) {
            s  += __shfl_down(s, off);
            ss += __shfl_down(ss, off);
        }
        const int wid = t >> 6, lane = t & 63;
        if (lane == 0) { smem[wid] = s; smem[wid + 4] = ss; }
        __syncthreads();
        if (t == 0) {
            float S  = smem[0] + smem[1] + smem[2] + smem[3];
            float SS = smem[4] + smem[5] + smem[6] + smem[7];
            float mu = S * (1.0f / 1024.0f);
            float var = SS * (1.0f / 1024.0f) - mu * mu;
            smem[0] = mu;
            smem[1] = rsqrtf(var + 1e-7f);
        }
        __syncthreads();
        const float mu = smem[0], rs = smem[1];
        const float4 g = ((const float4*)gamma)[t];
        const float4 be = ((const float4*)beta)[t];
        ushort4 pk;
        pk.x = f2bf((v.x - mu) * rs * g.x + be.x);
        pk.y = f2bf((v.y - mu) * rs * g.y + be.y);
        pk.z = f2bf((v.z - mu) * rs * g.z + be.z);
        pk.w = f2bf((v.w - mu) * rs * g.w + be.w);
        ((ushort4*)(Aout + (size_t)row * 1024))[t] = pk;
    } else {
        const int r = b - 16384;            // 4096 tiles: bx 0..127, by 0..31
        const int bx = r & 127;
        const int by = r >> 7;
        float (*tile)[33] = (float(*)[33])smem;
        const int tx = t & 31;
        const int ty = t >> 5;
        #pragma unroll
        for (int i = 0; i < 4; ++i) {
            int k = by * 32 + ty + i * 8;
            tile[ty + i * 8][tx] = W[(size_t)k * 4096 + bx * 32 + tx];
        }
        __syncthreads();
        #pragma unroll
        for (int i = 0; i < 4; ++i) {
            int n = bx * 32 + ty + i * 8;
            Wt[(size_t)n * 1024 + by * 32 + tx] = f2bf(tile[tx][ty + i * 8]);
        }
    }
}

// ---------------- GEMM 256x256, BK=64, dbuf 128KB, PERSISTENT ------------------
// R14 wait ledger with the publication barrier MOVED BEFORE compute:
//  per kt: stage B(kt+1); vmcnt(4) [retire A{i1,i3}(kt), keep B(kt+1) flying];
//          BARRIER [publish A-half1(kt)];
//          << single barrier-free region: 24 ds_reads + 64 MFMA + stage A(kt+1),
//             compiler interleaves reads under MFMAs via counted lgkmcnt >>
//          vmcnt(2) [retire B(kt+1)+A{i0,i2}(kt+1), keep A{i1,i3}(kt+1) flying];
//          BARRIER [publish B+A-half0 for kt+1; WAR-protect cbuf].
// Entry state of kt: published = B(kt) + A-half0(kt); in-flight = A{i1,i3}(kt).
// Tail (i==3, kt==15): no stages -> vmcnt(0) before the publication barrier
// (R13 lesson: vmcnt(4) with <=4 outstanding is a no-op). Tile transition
// (i<3, kt==15): stages target next tile's kt0; end wait = VM0 before epilogue
// so epilogue stores can't poison later counted waits.
__global__ __launch_bounds__(512, 1) void gemm_kernel(
    const unsigned short* __restrict__ A, const unsigned short* __restrict__ Wt,
    const float* __restrict__ bias, float* __restrict__ out) {
    __shared__ char lds_mem[131072];   // [2 bufs][A 32KB | B 32KB]

    const int bid = blockIdx.x;        // 0..255
    const int t = threadIdx.x;
    const int lane = t & 63;
    const int wid = t >> 6;            // 0..7
    const int wm = wid >> 2;           // 0..1  (M half)
    const int wn = wid & 3;            // 0..3  (N quarter)
    const int lrow = lane & 15;
    const int lk = lane >> 4;          // 0..3

    // staging: thread t -> row (t>>3)+64*i, 16B chunk (t&7); src pre-swizzled
    const int srr = t >> 3;            // 0..63
    const int sch = t & 7;
    const int sgc = sch ^ (srr & 7);
    const int lst = srr * 128 + sch * 16;

    // read-side swizzle: chunk c of frag-row r -> slot (c ^ (r&7)); r&7 == lrow&7
    const int ck0 = ((lk) ^ (lrow & 7)) * 16;
    const int ck1 = ((4 + lk) ^ (lrow & 7)) * 16;
    const int aBase = (wm * 128 + lrow) * 128;           // + mi*16*128, mi 0..7
    const int bBase = 32768 + (wn * 64 + lrow) * 128;    // + ni*16*128, ni 0..3

    char* lds0 = lds_mem;
    char* lds1 = lds_mem + 65536;

    const unsigned short *gA, *gB;
    int bm, bn;
    auto tileBase = [&](int tau) {
        const int swz = (tau & 7) * 128 + (tau >> 3);
        bm = swz >> 4;                 // 0..63
        bn = swz & 15;                 // 0..15
        gA = A  + (size_t)(bm * 256 + srr) * 1024 + sgc * 8;
        gB = Wt + (size_t)(bn * 256 + srr) * 1024 + sgc * 8;
    };

    auto stageB = [&](const unsigned short* pB, int kt, char* buf) {
        #pragma unroll
        for (int i = 0; i < 4; ++i)
            async_copy16(pB + (size_t)(i * 64) * 1024 + kt * 64,
                         buf + 32768 + i * 8192 + lst);
    };
    // order i0,i2,i1,i3 so the 2 NEWEST loads are regions {i1,i3} (A-half1)
    auto stageA = [&](const unsigned short* pA, int kt, char* buf) {
        async_copy16(pA + kt * 64,                      buf + lst);          // i0
        async_copy16(pA + (size_t)131072 + kt * 64,     buf + 16384 + lst);  // i2
        async_copy16(pA + (size_t)65536  + kt * 64,     buf + 8192  + lst);  // i1
        async_copy16(pA + (size_t)196608 + kt * 64,     buf + 24576 + lst);  // i3
    };

    // prologue: full kt=0 staged, FULL drain once
    tileBase(bid);
    stageB(gB, 0, lds0);
    stageA(gA, 0, lds0);
    VM0();
    BARRIER();

    const int NKT = 16;
    for (int i = 0; i < 4; ++i) {
        const int bmc = bm, bnc = bn;
        float bv[4];
        #pragma unroll
        for (int ni = 0; ni < 4; ++ni) bv[ni] = bias[bnc * 256 + wn * 64 + ni * 16 + lrow];

        f32x4 acc[8][4];
        #pragma unroll
        for (int a = 0; a < 8; ++a)
            #pragma unroll
            for (int j = 0; j < 4; ++j) acc[a][j] = (f32x4)0.0f;

        for (int kt = 0; kt < NKT; ++kt) {
            char* cbuf = (kt & 1) ? lds1 : lds0;
            char* nbuf = (kt & 1) ? lds0 : lds1;
            const bool haveNext = (kt < NKT - 1) || (i < 3);
            if (kt == NKT - 1 && i < 3) tileBase(bid + 256 * (i + 1));
            const int ktn = (kt < NKT - 1) ? kt + 1 : 0;

            // ---- publication point (no compute yet)
            if (haveNext) {
                stageB(gB, ktn, nbuf);
                VMCNT(4);            // retire A{i1,i3}(kt); B(kt+1) stays in flight
            } else {
                VM0();               // tail: nothing staged -> full drain covers A-half1
            }
            BARRIER();               // publish A-half1(kt) to all waves

            // ---- single barrier-free compute region: reads + MFMAs interleave
            __builtin_amdgcn_s_setprio(1);
            bf16x8 bf[4][2];
            #pragma unroll
            for (int ni = 0; ni < 4; ++ni) {
                const char* p = cbuf + bBase + ni * 16 * 128;
                bf[ni][0] = *(const bf16x8*)(p + ck0);
                bf[ni][1] = *(const bf16x8*)(p + ck1);
            }
            bf16x8 af[4][2];
            #pragma unroll
            for (int mi = 0; mi < 4; ++mi) {
                const char* p = cbuf + aBase + mi * 16 * 128;
                af[mi][0] = *(const bf16x8*)(p + ck0);
                af[mi][1] = *(const bf16x8*)(p + ck1);
            }
            #pragma unroll
            for (int mi = 0; mi < 4; ++mi)
                #pragma unroll
                for (int ni = 0; ni < 4; ++ni) {
                    acc[mi][ni] = __builtin_amdgcn_mfma_f32_16x16x32_bf16(af[mi][0], bf[ni][0], acc[mi][ni], 0, 0, 0);
                    acc[mi][ni] = __builtin_amdgcn_mfma_f32_16x16x32_bf16(af[mi][1], bf[ni][1], acc[mi][ni], 0, 0, 0);
                }
            bf16x8 ag[4][2];
            #pragma unroll
            for (int mi = 0; mi < 4; ++mi) {
                const char* p = cbuf + aBase + (64 + mi * 16) * 128;
                ag[mi][0] = *(const bf16x8*)(p + ck0);
                ag[mi][1] = *(const bf16x8*)(p + ck1);
            }
            if (haveNext) stageA(gA, ktn, nbuf);
            #pragma unroll
            for (int mi = 0; mi < 4; ++mi)
                #pragma unroll
                for (int ni = 0; ni < 4; ++ni) {
                    acc[4 + mi][ni] = __builtin_amdgcn_mfma_f32_16x16x32_bf16(ag[mi][0], bf[ni][0], acc[4 + mi][ni], 0, 0, 0);
                    acc[4 + mi][ni] = __builtin_amdgcn_mfma_f32_16x16x32_bf16(ag[mi][1], bf[ni][1], acc[4 + mi][ni], 0, 0, 0);
                }
            __builtin_amdgcn_s_setprio(0);

            // ---- end-of-kt wait + barrier
            if (kt == NKT - 1) {
                VM0();               // publish next tile's kt0 BEFORE epilogue
            } else {
                VMCNT(2);            // retire B(kt+1)+A{i0,i2}(kt+1); {i1,i3} fly
            }
            BARRIER();
        }

        // ---- epilogue: bias + fast gelu, fp32 store (no LDS, no barrier)
        #pragma unroll
        for (int mi = 0; mi < 8; ++mi) {
            const int row0 = bmc * 256 + wm * 128 + mi * 16 + lk * 4;
            #pragma unroll
            for (int ni = 0; ni < 4; ++ni) {
                const int col = bnc * 256 + wn * 64 + ni * 16 + lrow;
                #pragma unroll
                for (int r = 0; r < 4; ++r) {
                    float y = acc[mi][ni][r] + bv[ni];
                    out[(size_t)(row0 + r) * 4096 + col] = fast_gelu(y);
                }
            }
        }
    }
}

extern "C" void kernel_launch(void* const* d_in, const int* in_sizes, int n_in,
                              void* d_out, int out_size, void* d_ws, size_t ws_size,
                              hipStream_t stream) {
    const float* hidden = (const float*)d_in[0];
    const float* gamma  = (const float*)d_in[1];
    const float* beta   = (const float*)d_in[2];
    const float* W      = (const float*)d_in[3];
    const float* bias   = (const float*)d_in[4];
    float* out = (float*)d_out;

    unsigned short* Abf = (unsigned short*)d_ws;
    unsigned short* Wt  = (unsigned short*)((char*)d_ws + (size_t)16384 * 1024 * 2);

    prep_kernel<<<16384 + 4096, 256, 0, stream>>>(hidden, gamma, beta, Abf, W, Wt);
    gemm_kernel<<<256, 512, 0, stream>>>(Abf, Wt, bias, out);
}

// Round 17
// 184.187 us; speedup vs baseline: 1.0170x; 1.0170x over previous
//
#include <hip/hip_runtime.h>
#include <hip/hip_bf16.h>

typedef __attribute__((ext_vector_type(8))) short bf16x8;
typedef __attribute__((ext_vector_type(4))) float f32x4;

static __device__ __forceinline__ unsigned short f2bf(float f) {
    unsigned u = __builtin_bit_cast(unsigned, f);
    unsigned rounding = 0x7fffu + ((u >> 16) & 1u);
    u += rounding;
    return (unsigned short)(u >> 16);
}

static __device__ __forceinline__ void async_copy16(const void* g, void* l) {
    __builtin_amdgcn_global_load_lds(
        (const __attribute__((address_space(1))) unsigned int*)g,
        (__attribute__((address_space(3))) unsigned int*)l,
        16, 0, 0);
}

#define BARRIER() __builtin_amdgcn_s_barrier()
// counted waits: memory clobber only (no sched_barrier pin)
#define VMCNT_NS(N) asm volatile("s_waitcnt vmcnt(" #N ")" ::: "memory")
// full drains keep the scheduling fence
#define VM0() do { asm volatile("s_waitcnt vmcnt(0)" ::: "memory"); \
                   __builtin_amdgcn_sched_barrier(0); } while (0)

// fast erf-gelu via tanh approximation (|err| <= ~3e-3, threshold margin 0.07+)
static __device__ __forceinline__ float fast_gelu(float y) {
    float u = 0.7978845608028654f * y * (1.0f + 0.044715f * y * y);
    float au = fminf(fabsf(u), 9.0f);
    float e = __expf(-2.0f * au);
    float th = (1.0f - e) * __builtin_amdgcn_rcpf(1.0f + e);
    th = (u < 0.0f) ? -th : th;
    return 0.5f * y * (1.0f + th);
}

// ---------------- merged prep: LN(+bf16 cast) and W->Wt transpose-cast --------
__global__ __launch_bounds__(256) void prep_kernel(
    const float* __restrict__ x, const float* __restrict__ gamma,
    const float* __restrict__ beta, unsigned short* __restrict__ Aout,
    const float* __restrict__ W, unsigned short* __restrict__ Wt) {
    __shared__ float smem[33 * 32];
    const int b = blockIdx.x;
    const int t = threadIdx.x;

    if (b < 16384) {
        const int row = b;
        const float4 v = ((const float4*)(x + (size_t)row * 1024))[t];
        float s  = v.x + v.y + v.z + v.w;
        float ss = v.x * v.x + v.y * v.y + v.z * v.z + v.w * v.w;
        #pragma unroll
        for (int off = 32; off; off >>= 1) {
            s  += __shfl_down(s, off);
            ss += __shfl_down(ss, off);
        }
        const int wid = t >> 6, lane = t & 63;
        if (lane == 0) { smem[wid] = s; smem[wid + 4] = ss; }
        __syncthreads();
        if (t == 0) {
            float S  = smem[0] + smem[1] + smem[2] + smem[3];
            float SS = smem[4] + smem[5] + smem[6] + smem[7];
            float mu = S * (1.0f / 1024.0f);
            float var = SS * (1.0f / 1024.0f) - mu * mu;
            smem[0] = mu;
            smem[1] = rsqrtf(var + 1e-7f);
        }
        __syncthreads();
        const float mu = smem[0], rs = smem[1];
        const float4 g = ((const float4*)gamma)[t];
        const float4 be = ((const float4*)beta)[t];
        ushort4 pk;
        pk.x = f2bf((v.x - mu) * rs * g.x + be.x);
        pk.y = f2bf((v.y - mu) * rs * g.y + be.y);
        pk.z = f2bf((v.z - mu) * rs * g.z + be.z);
        pk.w = f2bf((v.w - mu) * rs * g.w + be.w);
        ((ushort4*)(Aout + (size_t)row * 1024))[t] = pk;
    } else {
        const int r = b - 16384;            // 4096 tiles: bx 0..127, by 0..31
        const int bx = r & 127;
        const int by = r >> 7;
        float (*tile)[33] = (float(*)[33])smem;
        const int tx = t & 31;
        const int ty = t >> 5;
        #pragma unroll
        for (int i = 0; i < 4; ++i) {
            int k = by * 32 + ty + i * 8;
            tile[ty + i * 8][tx] = W[(size_t)k * 4096 + bx * 32 + tx];
        }
        __syncthreads();
        #pragma unroll
        for (int i = 0; i < 4; ++i) {
            int n = bx * 32 + ty + i * 8;
            Wt[(size_t)n * 1024 + by * 32 + tx] = f2bf(tile[tx][ty + i * 8]);
        }
    }
}

// ---------------- GEMM 256x256, BK=64, dbuf 128KB, PERSISTENT, counted vmcnt ---
// R14 structure (best measured: 152.8us, MfmaUtil 39%) with 3 micro-changes:
//  - no s_setprio (m190: negative on non-8-phase GEMM)
//  - kt==0 skips the mid-kt wait+barrier (A-half1(0) already published by the
//    prologue/boundary VM0+BARRIER; no other publication/WAR role — audited)
//  - counted VMCNTs drop the sched_barrier pin (keep "memory" clobber)
// Wait ledger unchanged from R14:
//  P1: read B(kt)+A-h0(kt); stage B(kt+1); MFMA mi0-3; [kt>0] vmcnt(4); barrier
//  P2: read A-h1(kt); stage A(kt+1) order i0,i2,i1,i3; MFMA mi4-7; vmcnt(2); barrier
//  tail kt (no staging): end-P1 full drain (R13 lesson); kt==15 w/ next tile:
//  VM0 before epilogue so stores can't poison counted waits.
__global__ __launch_bounds__(512, 1) void gemm_kernel(
    const unsigned short* __restrict__ A, const unsigned short* __restrict__ Wt,
    const float* __restrict__ bias, float* __restrict__ out) {
    __shared__ char lds_mem[131072];   // [2 bufs][A 32KB | B 32KB]

    const int bid = blockIdx.x;        // 0..255
    const int t = threadIdx.x;
    const int lane = t & 63;
    const int wid = t >> 6;            // 0..7
    const int wm = wid >> 2;           // 0..1  (M half)
    const int wn = wid & 3;            // 0..3  (N quarter)
    const int lrow = lane & 15;
    const int lk = lane >> 4;          // 0..3

    // staging: thread t -> row (t>>3)+64*i, 16B chunk (t&7); src pre-swizzled
    const int srr = t >> 3;            // 0..63
    const int sch = t & 7;
    const int sgc = sch ^ (srr & 7);
    const int lst = srr * 128 + sch * 16;

    // read-side swizzle: chunk c of frag-row r -> slot (c ^ (r&7)); r&7 == lrow&7
    const int ck0 = ((lk) ^ (lrow & 7)) * 16;
    const int ck1 = ((4 + lk) ^ (lrow & 7)) * 16;
    const int aBase = (wm * 128 + lrow) * 128;           // + mi*16*128, mi 0..7
    const int bBase = 32768 + (wn * 64 + lrow) * 128;    // + ni*16*128, ni 0..3

    char* lds0 = lds_mem;
    char* lds1 = lds_mem + 65536;

    const unsigned short *gA, *gB;
    int bm, bn;
    auto tileBase = [&](int tau) {
        const int swz = (tau & 7) * 128 + (tau >> 3);
        bm = swz >> 4;                 // 0..63
        bn = swz & 15;                 // 0..15
        gA = A  + (size_t)(bm * 256 + srr) * 1024 + sgc * 8;
        gB = Wt + (size_t)(bn * 256 + srr) * 1024 + sgc * 8;
    };

    auto stageB = [&](const unsigned short* pB, int kt, char* buf) {
        #pragma unroll
        for (int i = 0; i < 4; ++i)
            async_copy16(pB + (size_t)(i * 64) * 1024 + kt * 64,
                         buf + 32768 + i * 8192 + lst);
    };
    // order i0,i2,i1,i3 so the 2 NEWEST loads are regions {i1,i3} (A-half1)
    auto stageA = [&](const unsigned short* pA, int kt, char* buf) {
        async_copy16(pA + kt * 64,                      buf + lst);          // i0
        async_copy16(pA + (size_t)131072 + kt * 64,     buf + 16384 + lst);  // i2
        async_copy16(pA + (size_t)65536  + kt * 64,     buf + 8192  + lst);  // i1
        async_copy16(pA + (size_t)196608 + kt * 64,     buf + 24576 + lst);  // i3
    };

    // prologue: full kt=0 staged, FULL drain once (publishes all of kt0)
    tileBase(bid);
    stageB(gB, 0, lds0);
    stageA(gA, 0, lds0);
    VM0();
    BARRIER();

    const int NKT = 16;
    for (int i = 0; i < 4; ++i) {
        const int bmc = bm, bnc = bn;
        float bv[4];
        #pragma unroll
        for (int ni = 0; ni < 4; ++ni) bv[ni] = bias[bnc * 256 + wn * 64 + ni * 16 + lrow];

        f32x4 acc[8][4];
        #pragma unroll
        for (int a = 0; a < 8; ++a)
            #pragma unroll
            for (int j = 0; j < 4; ++j) acc[a][j] = (f32x4)0.0f;

        for (int kt = 0; kt < NKT; ++kt) {
            char* cbuf = (kt & 1) ? lds1 : lds0;
            char* nbuf = (kt & 1) ? lds0 : lds1;
            const bool haveNext = (kt < NKT - 1) || (i < 3);
            if (kt == NKT - 1 && i < 3) tileBase(bid + 256 * (i + 1));
            const int ktn = (kt < NKT - 1) ? kt + 1 : 0;

            // ---- P1: B all + A-half0; stage B(next); MFMA mi0-3
            bf16x8 bf[4][2];
            #pragma unroll
            for (int ni = 0; ni < 4; ++ni) {
                const char* p = cbuf + bBase + ni * 16 * 128;
                bf[ni][0] = *(const bf16x8*)(p + ck0);
                bf[ni][1] = *(const bf16x8*)(p + ck1);
            }
            bf16x8 af[4][2];
            #pragma unroll
            for (int mi = 0; mi < 4; ++mi) {
                const char* p = cbuf + aBase + mi * 16 * 128;
                af[mi][0] = *(const bf16x8*)(p + ck0);
                af[mi][1] = *(const bf16x8*)(p + ck1);
            }
            if (haveNext) stageB(gB, ktn, nbuf);
            #pragma unroll
            for (int mi = 0; mi < 4; ++mi)
                #pragma unroll
                for (int ni = 0; ni < 4; ++ni) {
                    acc[mi][ni] = __builtin_amdgcn_mfma_f32_16x16x32_bf16(af[mi][0], bf[ni][0], acc[mi][ni], 0, 0, 0);
                    acc[mi][ni] = __builtin_amdgcn_mfma_f32_16x16x32_bf16(af[mi][1], bf[ni][1], acc[mi][ni], 0, 0, 0);
                }
            // mid-kt publication: only needed for kt>0 (kt==0's A-half1 was
            // published by the prologue/boundary VM0+BARRIER)
            if (kt > 0) {
                if (!haveNext) {
                    VM0();           // tail: nothing staged -> full drain covers A-h1
                } else {
                    VMCNT_NS(4);     // retire A(kt){i1,i3}; B(next) stays in flight
                }
                BARRIER();           // publish A-half1(kt)
            }

            // ---- P2: A-half1; stage A(next); MFMA mi4-7
            bf16x8 ag[4][2];
            #pragma unroll
            for (int mi = 0; mi < 4; ++mi) {
                const char* p = cbuf + aBase + (64 + mi * 16) * 128;
                ag[mi][0] = *(const bf16x8*)(p + ck0);
                ag[mi][1] = *(const bf16x8*)(p + ck1);
            }
            if (haveNext) stageA(gA, ktn, nbuf);
            #pragma unroll
            for (int mi = 0; mi < 4; ++mi)
                #pragma unroll
                for (int ni = 0; ni < 4; ++ni) {
                    acc[4 + mi][ni] = __builtin_amdgcn_mfma_f32_16x16x32_bf16(ag[mi][0], bf[ni][0], acc[4 + mi][ni], 0, 0, 0);
                    acc[4 + mi][ni] = __builtin_amdgcn_mfma_f32_16x16x32_bf16(ag[mi][1], bf[ni][1], acc[4 + mi][ni], 0, 0, 0);
                }
            if (kt == NKT - 1) {
                VM0();               // publish next tile's kt0 BEFORE epilogue
            } else {
                VMCNT_NS(2);         // retire B(kt+1)+A(kt+1){i0,i2}; {i1,i3} fly
            }
            BARRIER();
        }

        // ---- epilogue: bias + fast gelu, fp32 store (no LDS, no barrier)
        #pragma unroll
        for (int mi = 0; mi < 8; ++mi) {
            const int row0 = bmc * 256 + wm * 128 + mi * 16 + lk * 4;
            #pragma unroll
            for (int ni = 0; ni < 4; ++ni) {
                const int col = bnc * 256 + wn * 64 + ni * 16 + lrow;
                #pragma unroll
                for (int r = 0; r < 4; ++r) {
                    float y = acc[mi][ni][r] + bv[ni];
                    out[(size_t)(row0 + r) * 4096 + col] = fast_gelu(y);
                }
            }
        }
    }
}

extern "C" void kernel_launch(void* const* d_in, const int* in_sizes, int n_in,
                              void* d_out, int out_size, void* d_ws, size_t ws_size,
                              hipStream_t stream) {
    const float* hidden = (const float*)d_in[0];
    const float* gamma  = (const float*)d_in[1];
    const float* beta   = (const float*)d_in[2];
    const float* W      = (const float*)d_in[3];
    const float* bias   = (const float*)d_in[4];
    float* out = (float*)d_out;

    unsigned short* Abf = (unsigned short*)d_ws;
    unsigned short* Wt  = (unsigned short*)((char*)d_ws + (size_t)16384 * 1024 * 2);

    prep_kernel<<<16384 + 4096, 256, 0, stream>>>(hidden, gamma, beta, Abf, W, Wt);
    gemm_kernel<<<256, 512, 0, stream>>>(Abf, Wt, bias, out);
}

// Round 18
// 179.535 us; speedup vs baseline: 1.0433x; 1.0259x over previous
//
#include <hip/hip_runtime.h>
#include <hip/hip_bf16.h>

typedef __attribute__((ext_vector_type(8))) short bf16x8;
typedef __attribute__((ext_vector_type(4))) float f32x4;

static __device__ __forceinline__ unsigned short f2bf(float f) {
    unsigned u = __builtin_bit_cast(unsigned, f);
    unsigned rounding = 0x7fffu + ((u >> 16) & 1u);
    u += rounding;
    return (unsigned short)(u >> 16);
}

static __device__ __forceinline__ void async_copy16(const void* g, void* l) {
    __builtin_amdgcn_global_load_lds(
        (const __attribute__((address_space(1))) unsigned int*)g,
        (__attribute__((address_space(3))) unsigned int*)l,
        16, 0, 0);
}

#define BARRIER() __builtin_amdgcn_s_barrier()
#define VMCNT(N) do { asm volatile("s_waitcnt vmcnt(" #N ")" ::: "memory"); \
                      __builtin_amdgcn_sched_barrier(0); } while (0)
#define VM0() VMCNT(0)

// fast erf-gelu via tanh approximation (|err| <= ~3e-3, threshold margin 0.07+)
static __device__ __forceinline__ float fast_gelu(float y) {
    float u = 0.7978845608028654f * y * (1.0f + 0.044715f * y * y);
    float au = fminf(fabsf(u), 9.0f);
    float e = __expf(-2.0f * au);
    float th = (1.0f - e) * __builtin_amdgcn_rcpf(1.0f + e);
    th = (u < 0.0f) ? -th : th;
    return 0.5f * y * (1.0f + th);
}

// ---------------- merged prep: LN(+bf16 cast) and W->Wt transpose-cast --------
__global__ __launch_bounds__(256) void prep_kernel(
    const float* __restrict__ x, const float* __restrict__ gamma,
    const float* __restrict__ beta, unsigned short* __restrict__ Aout,
    const float* __restrict__ W, unsigned short* __restrict__ Wt) {
    __shared__ float smem[33 * 32];
    const int b = blockIdx.x;
    const int t = threadIdx.x;

    if (b < 16384) {
        const int row = b;
        const float4 v = ((const float4*)(x + (size_t)row * 1024))[t];
        float s  = v.x + v.y + v.z + v.w;
        float ss = v.x * v.x + v.y * v.y + v.z * v.z + v.w * v.w;
        #pragma unroll
        for (int off = 32; off; off >>= 1) {
            s  += __shfl_down(s, off);
            ss += __shfl_down(ss, off);
        }
        const int wid = t >> 6, lane = t & 63;
        if (lane == 0) { smem[wid] = s; smem[wid + 4] = ss; }
        __syncthreads();
        if (t == 0) {
            float S  = smem[0] + smem[1] + smem[2] + smem[3];
            float SS = smem[4] + smem[5] + smem[6] + smem[7];
            float mu = S * (1.0f / 1024.0f);
            float var = SS * (1.0f / 1024.0f) - mu * mu;
            smem[0] = mu;
            smem[1] = rsqrtf(var + 1e-7f);
        }
        __syncthreads();
        const float mu = smem[0], rs = smem[1];
        const float4 g = ((const float4*)gamma)[t];
        const float4 be = ((const float4*)beta)[t];
        ushort4 pk;
        pk.x = f2bf((v.x - mu) * rs * g.x + be.x);
        pk.y = f2bf((v.y - mu) * rs * g.y + be.y);
        pk.z = f2bf((v.z - mu) * rs * g.z + be.z);
        pk.w = f2bf((v.w - mu) * rs * g.w + be.w);
        ((ushort4*)(Aout + (size_t)row * 1024))[t] = pk;
    } else {
        const int r = b - 16384;            // 4096 tiles: bx 0..127, by 0..31
        const int bx = r & 127;
        const int by = r >> 7;
        float (*tile)[33] = (float(*)[33])smem;
        const int tx = t & 31;
        const int ty = t >> 5;
        #pragma unroll
        for (int i = 0; i < 4; ++i) {
            int k = by * 32 + ty + i * 8;
            tile[ty + i * 8][tx] = W[(size_t)k * 4096 + bx * 32 + tx];
        }
        __syncthreads();
        #pragma unroll
        for (int i = 0; i < 4; ++i) {
            int n = bx * 32 + ty + i * 8;
            Wt[(size_t)n * 1024 + by * 32 + tx] = f2bf(tile[tx][ty + i * 8]);
        }
    }
}

// ---------------- GEMM 256x256, BK=64, dbuf 128KB, PERSISTENT, counted vmcnt ---
// R14 VERBATIM structure (best measured: gemm 152.8us, MfmaUtil 39%) +
// nontemporal epilogue stores (out is write-once; keep L2 for A/Wt panels).
// Wait ledger (in-order retire; counted-wait-before-barrier = global prefix):
//  P1: read B(kt)+A-h0(kt); stage B(kt+1); MFMA mi0-3;
//      [no staging issued] VM0  else [kt>0] VMCNT(4);  barrier
//  P2: read A-h1(kt); stage A(kt+1) order i0,i2,i1,i3; MFMA mi4-7;
//      [kt==15] VM0 (publish next tile kt0 pre-epilogue)  else VMCNT(2); barrier
__global__ __launch_bounds__(512, 1) void gemm_kernel(
    const unsigned short* __restrict__ A, const unsigned short* __restrict__ Wt,
    const float* __restrict__ bias, float* __restrict__ out) {
    __shared__ char lds_mem[131072];   // [2 bufs][A 32KB | B 32KB]

    const int bid = blockIdx.x;        // 0..255
    const int t = threadIdx.x;
    const int lane = t & 63;
    const int wid = t >> 6;            // 0..7
    const int wm = wid >> 2;           // 0..1  (M half)
    const int wn = wid & 3;            // 0..3  (N quarter)
    const int lrow = lane & 15;
    const int lk = lane >> 4;          // 0..3

    // staging: thread t -> row (t>>3)+64*i, 16B chunk (t&7); src pre-swizzled
    const int srr = t >> 3;            // 0..63
    const int sch = t & 7;
    const int sgc = sch ^ (srr & 7);
    const int lst = srr * 128 + sch * 16;

    // read-side swizzle: chunk c of frag-row r -> slot (c ^ (r&7)); r&7 == lrow&7
    const int ck0 = ((lk) ^ (lrow & 7)) * 16;
    const int ck1 = ((4 + lk) ^ (lrow & 7)) * 16;
    const int aBase = (wm * 128 + lrow) * 128;           // + mi*16*128, mi 0..7
    const int bBase = 32768 + (wn * 64 + lrow) * 128;    // + ni*16*128, ni 0..3

    char* lds0 = lds_mem;
    char* lds1 = lds_mem + 65536;

    const unsigned short *gA, *gB;
    int bm, bn;
    auto tileBase = [&](int tau) {
        const int swz = (tau & 7) * 128 + (tau >> 3);
        bm = swz >> 4;                 // 0..63
        bn = swz & 15;                 // 0..15
        gA = A  + (size_t)(bm * 256 + srr) * 1024 + sgc * 8;
        gB = Wt + (size_t)(bn * 256 + srr) * 1024 + sgc * 8;
    };

    auto stageB = [&](const unsigned short* pB, int kt, char* buf) {
        #pragma unroll
        for (int i = 0; i < 4; ++i)
            async_copy16(pB + (size_t)(i * 64) * 1024 + kt * 64,
                         buf + 32768 + i * 8192 + lst);
    };
    // order i0,i2,i1,i3 so the 2 NEWEST loads are regions {i1,i3} (A-half1)
    auto stageA = [&](const unsigned short* pA, int kt, char* buf) {
        async_copy16(pA + kt * 64,                      buf + lst);          // i0
        async_copy16(pA + (size_t)131072 + kt * 64,     buf + 16384 + lst);  // i2
        async_copy16(pA + (size_t)65536  + kt * 64,     buf + 8192  + lst);  // i1
        async_copy16(pA + (size_t)196608 + kt * 64,     buf + 24576 + lst);  // i3
    };

    // prologue: full kt=0 staged, FULL drain once
    tileBase(bid);
    stageB(gB, 0, lds0);
    stageA(gA, 0, lds0);
    VM0();
    BARRIER();

    const int NKT = 16;
    for (int i = 0; i < 4; ++i) {
        const int bmc = bm, bnc = bn;
        float bv[4];
        #pragma unroll
        for (int ni = 0; ni < 4; ++ni) bv[ni] = bias[bnc * 256 + wn * 64 + ni * 16 + lrow];

        f32x4 acc[8][4];
        #pragma unroll
        for (int a = 0; a < 8; ++a)
            #pragma unroll
            for (int j = 0; j < 4; ++j) acc[a][j] = (f32x4)0.0f;

        for (int kt = 0; kt < NKT; ++kt) {
            char* cbuf = (kt & 1) ? lds1 : lds0;
            char* nbuf = (kt & 1) ? lds0 : lds1;
            const bool haveNext = (kt < NKT - 1) || (i < 3);
            if (kt == NKT - 1 && i < 3) tileBase(bid + 256 * (i + 1));
            const int ktn = (kt < NKT - 1) ? kt + 1 : 0;

            // ---- P1: B all + A-half0; stage B(next); MFMA mi0-3
            bf16x8 bf[4][2];
            #pragma unroll
            for (int ni = 0; ni < 4; ++ni) {
                const char* p = cbuf + bBase + ni * 16 * 128;
                bf[ni][0] = *(const bf16x8*)(p + ck0);
                bf[ni][1] = *(const bf16x8*)(p + ck1);
            }
            bf16x8 af[4][2];
            #pragma unroll
            for (int mi = 0; mi < 4; ++mi) {
                const char* p = cbuf + aBase + mi * 16 * 128;
                af[mi][0] = *(const bf16x8*)(p + ck0);
                af[mi][1] = *(const bf16x8*)(p + ck1);
            }
            if (haveNext) stageB(gB, ktn, nbuf);
            __builtin_amdgcn_s_setprio(1);
            #pragma unroll
            for (int mi = 0; mi < 4; ++mi)
                #pragma unroll
                for (int ni = 0; ni < 4; ++ni) {
                    acc[mi][ni] = __builtin_amdgcn_mfma_f32_16x16x32_bf16(af[mi][0], bf[ni][0], acc[mi][ni], 0, 0, 0);
                    acc[mi][ni] = __builtin_amdgcn_mfma_f32_16x16x32_bf16(af[mi][1], bf[ni][1], acc[mi][ni], 0, 0, 0);
                }
            __builtin_amdgcn_s_setprio(0);
            if (!haveNext) {
                VM0();               // no staging issued -> full drain covers A-h1
            } else if (kt > 0) {
                VMCNT(4);            // A(kt){i1,i3} landed; B(next) may fly
            }
            BARRIER();

            // ---- P2: A-half1; stage A(next); MFMA mi4-7
            bf16x8 ag[4][2];
            #pragma unroll
            for (int mi = 0; mi < 4; ++mi) {
                const char* p = cbuf + aBase + (64 + mi * 16) * 128;
                ag[mi][0] = *(const bf16x8*)(p + ck0);
                ag[mi][1] = *(const bf16x8*)(p + ck1);
            }
            if (haveNext) stageA(gA, ktn, nbuf);
            __builtin_amdgcn_s_setprio(1);
            #pragma unroll
            for (int mi = 0; mi < 4; ++mi)
                #pragma unroll
                for (int ni = 0; ni < 4; ++ni) {
                    acc[4 + mi][ni] = __builtin_amdgcn_mfma_f32_16x16x32_bf16(ag[mi][0], bf[ni][0], acc[4 + mi][ni], 0, 0, 0);
                    acc[4 + mi][ni] = __builtin_amdgcn_mfma_f32_16x16x32_bf16(ag[mi][1], bf[ni][1], acc[4 + mi][ni], 0, 0, 0);
                }
            __builtin_amdgcn_s_setprio(0);
            if (kt == NKT - 1) {
                VM0();               // publish next tile's kt0 BEFORE epilogue
            } else {
                VMCNT(2);            // B(kt+1)+A(kt+1){i0,i2} landed; {i1,i3} fly
            }
            BARRIER();
        }

        // ---- epilogue: bias + fast gelu, NONTEMPORAL fp32 store (write-once)
        #pragma unroll
        for (int mi = 0; mi < 8; ++mi) {
            const int row0 = bmc * 256 + wm * 128 + mi * 16 + lk * 4;
            #pragma unroll
            for (int ni = 0; ni < 4; ++ni) {
                const int col = bnc * 256 + wn * 64 + ni * 16 + lrow;
                #pragma unroll
                for (int r = 0; r < 4; ++r) {
                    float y = acc[mi][ni][r] + bv[ni];
                    __builtin_nontemporal_store(fast_gelu(y),
                        out + (size_t)(row0 + r) * 4096 + col);
                }
            }
        }
    }
}

extern "C" void kernel_launch(void* const* d_in, const int* in_sizes, int n_in,
                              void* d_out, int out_size, void* d_ws, size_t ws_size,
                              hipStream_t stream) {
    const float* hidden = (const float*)d_in[0];
    const float* gamma  = (const float*)d_in[1];
    const float* beta   = (const float*)d_in[2];
    const float* W      = (const float*)d_in[3];
    const float* bias   = (const float*)d_in[4];
    float* out = (float*)d_out;

    unsigned short* Abf = (unsigned short*)d_ws;
    unsigned short* Wt  = (unsigned short*)((char*)d_ws + (size_t)16384 * 1024 * 2);

    prep_kernel<<<16384 + 4096, 256, 0, stream>>>(hidden, gamma, beta, Abf, W, Wt);
    gemm_kernel<<<256, 512, 0, stream>>>(Abf, Wt, bias, out);
}

// Round 19
// 177.784 us; speedup vs baseline: 1.0536x; 1.0098x over previous
//
#include <hip/hip_runtime.h>
#include <hip/hip_bf16.h>

typedef __attribute__((ext_vector_type(8))) short bf16x8;
typedef __attribute__((ext_vector_type(4))) float f32x4;

static __device__ __forceinline__ unsigned short f2bf(float f) {
    unsigned u = __builtin_bit_cast(unsigned, f);
    unsigned rounding = 0x7fffu + ((u >> 16) & 1u);
    u += rounding;
    return (unsigned short)(u >> 16);
}

static __device__ __forceinline__ void async_copy16(const void* g, void* l) {
    __builtin_amdgcn_global_load_lds(
        (const __attribute__((address_space(1))) unsigned int*)g,
        (__attribute__((address_space(3))) unsigned int*)l,
        16, 0, 0);
}

#define BARRIER() __builtin_amdgcn_s_barrier()
#define VMCNT(N) do { asm volatile("s_waitcnt vmcnt(" #N ")" ::: "memory"); \
                      __builtin_amdgcn_sched_barrier(0); } while (0)
#define VM0() VMCNT(0)

// fast erf-gelu via tanh approximation (|err| <= ~3e-3, threshold margin 0.07+)
static __device__ __forceinline__ float fast_gelu(float y) {
    float u = 0.7978845608028654f * y * (1.0f + 0.044715f * y * y);
    float au = fminf(fabsf(u), 9.0f);
    float e = __expf(-2.0f * au);
    float th = (1.0f - e) * __builtin_amdgcn_rcpf(1.0f + e);
    th = (u < 0.0f) ? -th : th;
    return 0.5f * y * (1.0f + th);
}

// ---------------- merged prep: LN(+bf16 cast) and W->Wt transpose-cast --------
__global__ __launch_bounds__(256) void prep_kernel(
    const float* __restrict__ x, const float* __restrict__ gamma,
    const float* __restrict__ beta, unsigned short* __restrict__ Aout,
    const float* __restrict__ W, unsigned short* __restrict__ Wt) {
    __shared__ float smem[33 * 32];
    const int b = blockIdx.x;
    const int t = threadIdx.x;

    if (b < 16384) {
        const int row = b;
        const float4 v = ((const float4*)(x + (size_t)row * 1024))[t];
        float s  = v.x + v.y + v.z + v.w;
        float ss = v.x * v.x + v.y * v.y + v.z * v.z + v.w * v.w;
        #pragma unroll
        for (int off = 32; off; off >>= 1) {
            s  += __shfl_down(s, off);
            ss += __shfl_down(ss, off);
        }
        const int wid = t >> 6, lane = t & 63;
        if (lane == 0) { smem[wid] = s; smem[wid + 4] = ss; }
        __syncthreads();
        if (t == 0) {
            float S  = smem[0] + smem[1] + smem[2] + smem[3];
            float SS = smem[4] + smem[5] + smem[6] + smem[7];
            float mu = S * (1.0f / 1024.0f);
            float var = SS * (1.0f / 1024.0f) - mu * mu;
            smem[0] = mu;
            smem[1] = rsqrtf(var + 1e-7f);
        }
        __syncthreads();
        const float mu = smem[0], rs = smem[1];
        const float4 g = ((const float4*)gamma)[t];
        const float4 be = ((const float4*)beta)[t];
        ushort4 pk;
        pk.x = f2bf((v.x - mu) * rs * g.x + be.x);
        pk.y = f2bf((v.y - mu) * rs * g.y + be.y);
        pk.z = f2bf((v.z - mu) * rs * g.z + be.z);
        pk.w = f2bf((v.w - mu) * rs * g.w + be.w);
        ((ushort4*)(Aout + (size_t)row * 1024))[t] = pk;
    } else {
        const int r = b - 16384;            // 4096 tiles: bx 0..127, by 0..31
        const int bx = r & 127;
        const int by = r >> 7;
        float (*tile)[33] = (float(*)[33])smem;
        const int tx = t & 31;
        const int ty = t >> 5;
        #pragma unroll
        for (int i = 0; i < 4; ++i) {
            int k = by * 32 + ty + i * 8;
            tile[ty + i * 8][tx] = W[(size_t)k * 4096 + bx * 32 + tx];
        }
        __syncthreads();
        #pragma unroll
        for (int i = 0; i < 4; ++i) {
            int n = bx * 32 + ty + i * 8;
            Wt[(size_t)n * 1024 + by * 32 + tx] = f2bf(tile[tx][ty + i * 8]);
        }
    }
}

// ---------------- GEMM 256x256, BK=64, dbuf 128KB, PERSISTENT, counted vmcnt ---
// R14 anchor (best measured: gemm 152.8us / 899 TF, MfmaUtil 39%).
// Wait ledger (in-order retire; counted-wait-before-barrier = global prefix):
//  P1: read B(kt)+A-h0(kt); stage B(kt+1); MFMA mi0-3;
//      [no staging issued] VM0  else [kt>0] VMCNT(4);  barrier
//  P2: read A-h1(kt); stage A(kt+1) order i0,i2,i1,i3; MFMA mi4-7;
//      [kt==15] VM0 (publish next tile kt0 pre-epilogue)  else VMCNT(2); barrier
__global__ __launch_bounds__(512, 1) void gemm_kernel(
    const unsigned short* __restrict__ A, const unsigned short* __restrict__ Wt,
    const float* __restrict__ bias, float* __restrict__ out) {
    __shared__ char lds_mem[131072];   // [2 bufs][A 32KB | B 32KB]

    const int bid = blockIdx.x;        // 0..255
    const int t = threadIdx.x;
    const int lane = t & 63;
    const int wid = t >> 6;            // 0..7
    const int wm = wid >> 2;           // 0..1  (M half)
    const int wn = wid & 3;            // 0..3  (N quarter)
    const int lrow = lane & 15;
    const int lk = lane >> 4;          // 0..3

    // staging: thread t -> row (t>>3)+64*i, 16B chunk (t&7); src pre-swizzled
    const int srr = t >> 3;            // 0..63
    const int sch = t & 7;
    const int sgc = sch ^ (srr & 7);
    const int lst = srr * 128 + sch * 16;

    // read-side swizzle: chunk c of frag-row r -> slot (c ^ (r&7)); r&7 == lrow&7
    const int ck0 = ((lk) ^ (lrow & 7)) * 16;
    const int ck1 = ((4 + lk) ^ (lrow & 7)) * 16;
    const int aBase = (wm * 128 + lrow) * 128;           // + mi*16*128, mi 0..7
    const int bBase = 32768 + (wn * 64 + lrow) * 128;    // + ni*16*128, ni 0..3

    char* lds0 = lds_mem;
    char* lds1 = lds_mem + 65536;

    const unsigned short *gA, *gB;
    int bm, bn;
    auto tileBase = [&](int tau) {
        const int swz = (tau & 7) * 128 + (tau >> 3);
        bm = swz >> 4;                 // 0..63
        bn = swz & 15;                 // 0..15
        gA = A  + (size_t)(bm * 256 + srr) * 1024 + sgc * 8;
        gB = Wt + (size_t)(bn * 256 + srr) * 1024 + sgc * 8;
    };

    auto stageB = [&](const unsigned short* pB, int kt, char* buf) {
        #pragma unroll
        for (int i = 0; i < 4; ++i)
            async_copy16(pB + (size_t)(i * 64) * 1024 + kt * 64,
                         buf + 32768 + i * 8192 + lst);
    };
    // order i0,i2,i1,i3 so the 2 NEWEST loads are regions {i1,i3} (A-half1)
    auto stageA = [&](const unsigned short* pA, int kt, char* buf) {
        async_copy16(pA + kt * 64,                      buf + lst);          // i0
        async_copy16(pA + (size_t)131072 + kt * 64,     buf + 16384 + lst);  // i2
        async_copy16(pA + (size_t)65536  + kt * 64,     buf + 8192  + lst);  // i1
        async_copy16(pA + (size_t)196608 + kt * 64,     buf + 24576 + lst);  // i3
    };

    // prologue: full kt=0 staged, FULL drain once
    tileBase(bid);
    stageB(gB, 0, lds0);
    stageA(gA, 0, lds0);
    VM0();
    BARRIER();

    const int NKT = 16;
    for (int i = 0; i < 4; ++i) {
        const int bmc = bm, bnc = bn;
        float bv[4];
        #pragma unroll
        for (int ni = 0; ni < 4; ++ni) bv[ni] = bias[bnc * 256 + wn * 64 + ni * 16 + lrow];

        f32x4 acc[8][4];
        #pragma unroll
        for (int a = 0; a < 8; ++a)
            #pragma unroll
            for (int j = 0; j < 4; ++j) acc[a][j] = (f32x4)0.0f;

        for (int kt = 0; kt < NKT; ++kt) {
            char* cbuf = (kt & 1) ? lds1 : lds0;
            char* nbuf = (kt & 1) ? lds0 : lds1;
            const bool haveNext = (kt < NKT - 1) || (i < 3);
            if (kt == NKT - 1 && i < 3) tileBase(bid + 256 * (i + 1));
            const int ktn = (kt < NKT - 1) ? kt + 1 : 0;

            // ---- P1: B all + A-half0; stage B(next); MFMA mi0-3
            bf16x8 bf[4][2];
            #pragma unroll
            for (int ni = 0; ni < 4; ++ni) {
                const char* p = cbuf + bBase + ni * 16 * 128;
                bf[ni][0] = *(const bf16x8*)(p + ck0);
                bf[ni][1] = *(const bf16x8*)(p + ck1);
            }
            bf16x8 af[4][2];
            #pragma unroll
            for (int mi = 0; mi < 4; ++mi) {
                const char* p = cbuf + aBase + mi * 16 * 128;
                af[mi][0] = *(const bf16x8*)(p + ck0);
                af[mi][1] = *(const bf16x8*)(p + ck1);
            }
            if (haveNext) stageB(gB, ktn, nbuf);
            __builtin_amdgcn_s_setprio(1);
            #pragma unroll
            for (int mi = 0; mi < 4; ++mi)
                #pragma unroll
                for (int ni = 0; ni < 4; ++ni) {
                    acc[mi][ni] = __builtin_amdgcn_mfma_f32_16x16x32_bf16(af[mi][0], bf[ni][0], acc[mi][ni], 0, 0, 0);
                    acc[mi][ni] = __builtin_amdgcn_mfma_f32_16x16x32_bf16(af[mi][1], bf[ni][1], acc[mi][ni], 0, 0, 0);
                }
            __builtin_amdgcn_s_setprio(0);
            if (!haveNext) {
                VM0();               // no staging issued -> full drain covers A-h1
            } else if (kt > 0) {
                VMCNT(4);            // A(kt){i1,i3} landed; B(next) may fly
            }
            BARRIER();

            // ---- P2: A-half1; stage A(next); MFMA mi4-7
            bf16x8 ag[4][2];
            #pragma unroll
            for (int mi = 0; mi < 4; ++mi) {
                const char* p = cbuf + aBase + (64 + mi * 16) * 128;
                ag[mi][0] = *(const bf16x8*)(p + ck0);
                ag[mi][1] = *(const bf16x8*)(p + ck1);
            }
            if (haveNext) stageA(gA, ktn, nbuf);
            __builtin_amdgcn_s_setprio(1);
            #pragma unroll
            for (int mi = 0; mi < 4; ++mi)
                #pragma unroll
                for (int ni = 0; ni < 4; ++ni) {
                    acc[4 + mi][ni] = __builtin_amdgcn_mfma_f32_16x16x32_bf16(ag[mi][0], bf[ni][0], acc[4 + mi][ni], 0, 0, 0);
                    acc[4 + mi][ni] = __builtin_amdgcn_mfma_f32_16x16x32_bf16(ag[mi][1], bf[ni][1], acc[4 + mi][ni], 0, 0, 0);
                }
            __builtin_amdgcn_s_setprio(0);
            if (kt == NKT - 1) {
                VM0();               // publish next tile's kt0 BEFORE epilogue
            } else {
                VMCNT(2);            // B(kt+1)+A(kt+1){i0,i2} landed; {i1,i3} fly
            }
            BARRIER();
        }

        // ---- epilogue: bias + fast gelu, fp32 store (no LDS, no barrier)
        #pragma unroll
        for (int mi = 0; mi < 8; ++mi) {
            const int row0 = bmc * 256 + wm * 128 + mi * 16 + lk * 4;
            #pragma unroll
            for (int ni = 0; ni < 4; ++ni) {
                const int col = bnc * 256 + wn * 64 + ni * 16 + lrow;
                #pragma unroll
                for (int r = 0; r < 4; ++r) {
                    float y = acc[mi][ni][r] + bv[ni];
                    out[(size_t)(row0 + r) * 4096 + col] = fast_gelu(y);
                }
            }
        }
    }
}

extern "C" void kernel_launch(void* const* d_in, const int* in_sizes, int n_in,
                              void* d_out, int out_size, void* d_ws, size_t ws_size,
                              hipStream_t stream) {
    const float* hidden = (const float*)d_in[0];
    const float* gamma  = (const float*)d_in[1];
    const float* beta   = (const float*)d_in[2];
    const float* W      = (const float*)d_in[3];
    const float* bias   = (const float*)d_in[4];
    float* out = (float*)d_out;

    unsigned short* Abf = (unsigned short*)d_ws;
    unsigned short* Wt  = (unsigned short*)((char*)d_ws + (size_t)16384 * 1024 * 2);

    prep_kernel<<<16384 + 4096, 256, 0, stream>>>(hidden, gamma, beta, Abf, W, Wt);
    gemm_kernel<<<256, 512, 0, stream>>>(Abf, Wt, bias, out);
}